// Round 1
// 84.736 us; speedup vs baseline: 1.0192x; 1.0192x over previous
//
#include <hip/hip_runtime.h>
#include <math.h>

#define HXc 3.0f
#define HZc 0.25f
// JZ = -1.0f is folded into F (= HZ*V + HX*U - Z) and K (= S - A*G).

// ws layout (float offsets)
#define OFF_TANR 0         // [256*256] tan(theta) row-major [m][l]
#define OFF_TANT 65536     // [256*256] transposed [l][m]
#define OFF_CPR  131072    // [256] per-row product of cos(theta)
#define OFF_DNT  131328    // [1024*256] per-quarterblock partial dN_dtheta/2
#define OFF_DDT  393472    // [1024*256]
#define OFF_NM   655616    // [1024]
#define OFF_DM   656640    // [1024]
#define OFF_CN   657664    // [1024]
#define OFF_CD   658688    // [1024]

__device__ __forceinline__ float tan_poly(float x) {
    // |x| <= 0.3: tan x = x(1 + y(1/3 + y(2/15 + y(17/315 + y*62/2835)))), y=x^2
    float y = x * x;
    float p = fmaf(y, 62.0f / 2835.0f, 17.0f / 315.0f);
    p = fmaf(y, p, 2.0f / 15.0f);
    p = fmaf(y, p, 1.0f / 3.0f);
    return x * fmaf(y, p, 1.0f);
}

__device__ __forceinline__ float cos_poly(float x) {
    float y = x * x;
    float p = fmaf(y, 1.0f / 40320.0f, -1.0f / 720.0f);
    p = fmaf(y, p, 1.0f / 24.0f);
    p = fmaf(y, p, -0.5f);
    return fmaf(y, p, 1.0f);
}

// block = m, thread = l: tan tables (row + transposed) + per-row cos product.
__global__ __launch_bounds__(256) void k_prep(const float* __restrict__ theta,
                                              float* __restrict__ ws) {
    int m = blockIdx.x, t = threadIdx.x;
    float x = theta[m * 256 + t];
    float tn = tan_poly(x);
    float c = cos_poly(x);
    ws[OFF_TANR + m * 256 + t] = tn;
    ws[OFF_TANT + t * 256 + m] = tn;
    float pr = c;
    for (int o = 32; o; o >>= 1) pr *= __shfl_xor(pr, o);
    __shared__ float pp[4];
    if ((t & 63) == 0) pp[t >> 6] = pr;
    __syncthreads();
    if (t == 0) ws[OFF_CPR + m] = pp[0] * pp[1] * pp[2] * pp[3];
}

// 1024 blocks (g = m*4 + quarter, quarter owns 64 b's) x 512 threads (8 waves).
// Phase A: wave = l-segment of 32, lane = local column. 32 iters/thread.
// Phase B: wave = 8-b chunk, lane = 4 consecutive l's. 8 iters/thread.
__global__ __launch_bounds__(512, 6) void k_main(
        const float* __restrict__ coef,
        const float* __restrict__ strengths,
        float* __restrict__ ws) {
    int g = blockIdx.x;
    int m = g >> 2;
    int boff = (g & 3) * 64;
    int tid = threadIdx.x;
    int w = tid >> 6, lane = tid & 63;
    const float* __restrict__ tanR = ws + OFF_TANR;
    const float* __restrict__ tanT = ws + OFF_TANT;
    const float* __restrict__ Cpr = ws + OFF_CPR;

    __shared__ float sPad[257];          // sPad[l] = strengths[l-1], ends zeroed
    __shared__ float tmL[256];           // tan row m
    __shared__ float4 seg[8][64];        // phase-A partials (pw,u,v,z)
    __shared__ float Flds[64], cPlds[64];
    __shared__ float gN[2048];
    __shared__ float gD[2048];

    if (tid < 256) {
        tmL[tid] = tanR[m * 256 + tid];
        sPad[tid + 1] = (tid < 255) ? strengths[tid] : 0.0f;
    }
    if (tid == 256) sPad[0] = 0.0f;
    __syncthreads();

    // ---- Phase A: forward partials over 32 l's per wave ----
    {
        int b = boff + lane;
        int l0 = w * 32;
        const float* __restrict__ tcol = tanT + b;   // tcol[l*256]
        float pw = 1.0f, u = 0.0f, v = 0.0f, z = 0.0f, a_prev = 0.0f;
        if (w) {
            float qq = tmL[l0 - 1] * tcol[(l0 - 1) * 256];
            a_prev = (1.0f - qq) * __builtin_amdgcn_rcpf(1.0f + qq);
        }
#pragma unroll 8
        for (int l = l0; l < l0 + 32; ++l) {
            float tm = tmL[l];                 // LDS broadcast
            float tb = tcol[l * 256];          // coalesced global (L2)
            float qq = tm * tb;
            float w1 = 1.0f + qq;
            float inv = __builtin_amdgcn_rcpf(w1);
            pw *= w1;
            u = fmaf(tm + tb, inv, u);         // sins/cosd
            float a = (1.0f - qq) * inv;       // coss/cosd
            v += a;
            z = fmaf(sPad[l] * a_prev, a, z);  // chain Szz term
            a_prev = a;
        }
        seg[w][lane] = make_float4(pw, u, v, z);
    }
    __syncthreads();

    // ---- Combine segments: F/cP to LDS, per-block N/D partial sums ----
    if (tid < 64) {
        float pw = 1.0f, u = 0.0f, v = 0.0f, z = 0.0f;
#pragma unroll
        for (int q = 0; q < 8; ++q) {
            float4 s = seg[q][tid];
            pw *= s.x; u += s.y; v += s.z; z += s.w;
        }
        int b = boff + tid;
        float P = Cpr[m] * Cpr[b] * pw;
        float F = fmaf(HZc, v, fmaf(HXc, u, -z));    // JZ = -1
        float cP = coef[b] * P;
        Flds[tid] = F;
        cPlds[tid] = cP;
        float base = coef[m] * cP;
        float s1 = base, s2 = base * F, s3 = cP, s4 = cP * F;
        for (int o = 32; o; o >>= 1) {
            s1 += __shfl_xor(s1, o);
            s2 += __shfl_xor(s2, o);
            s3 += __shfl_xor(s3, o);
            s4 += __shfl_xor(s4, o);
        }
        if (tid == 0) {
            ws[OFF_DM + g] = s1;
            ws[OFF_NM + g] = s2;
            ws[OFF_CD + g] = s3;
            ws[OFF_CN + g] = s4;
        }
    }
    __syncthreads();

    // ---- Phase B: gradient ----
    {
        int l0 = lane * 4;
        float coefm = coef[m];
        float4 tm4 = *(const float4*)&tmL[l0];
        float tm[4] = {tm4.x, tm4.y, tm4.z, tm4.w};
        float sL[4], sR[4];
#pragma unroll
        for (int j = 0; j < 4; ++j) {
            sL[j] = sPad[l0 + j];        // strength of edge (l-1,l)
            sR[j] = sPad[l0 + j + 1];    // strength of edge (l,l+1)
        }
        float pN[4] = {0.f, 0.f, 0.f, 0.f};
        float pD[4] = {0.f, 0.f, 0.f, 0.f};

#pragma unroll 2
        for (int i = 0; i < 8; ++i) {
            int bl = w * 8 + i;
            int b = boff + bl;
            float4 tb4 = *(const float4*)&tanR[b * 256 + l0];
            float tb[4] = {tb4.x, tb4.y, tb4.z, tb4.w};
            float Fv = Flds[bl];
            float base = coefm * cPlds[bl];

            float A[4], S[4], G[4];
#pragma unroll
            for (int j = 0; j < 4; ++j) {
                float qq = tm[j] * tb[j];
                float inv = __builtin_amdgcn_rcpf(1.0f + qq);
                A[j] = (1.0f - qq) * inv;
                S[j] = (tm[j] + tb[j]) * inv;
                G[j] = (tm[j] - tb[j]) * inv;
            }
            float aLn = __shfl_up(A[3], 1);
            if (lane == 0) aLn = 0.0f;
            float aRn = __shfl_down(A[0], 1);
            if (lane == 63) aRn = 0.0f;
            float am1[4] = {aLn, A[0], A[1], A[2]};
            float ap1[4] = {A[1], A[2], A[3], aRn};
#pragma unroll
            for (int j = 0; j < 4; ++j) {
                float Gxz = fmaf(fmaf(HZc, A[j], HXc * S[j]), G[j],
                                 fmaf(HXc, A[j], -HZc * S[j]));
                float K = fmaf(-A[j], G[j], S[j]);          // JZ=-1 folded
                float inc = fmaf(sR[j], ap1[j], sL[j] * am1[j]);
                float term = fmaf(Fv, -G[j], fmaf(K, inc, Gxz));
                pN[j] = fmaf(base, term, pN[j]);
                pD[j] = fmaf(base, -G[j], pD[j]);
            }
        }
        ((float4*)gN)[w * 64 + lane] = make_float4(pN[0], pN[1], pN[2], pN[3]);
        ((float4*)gD)[w * 64 + lane] = make_float4(pD[0], pD[1], pD[2], pD[3]);
    }
    __syncthreads();
    if (tid < 256) {
        float sn = 0.0f, sd = 0.0f;
#pragma unroll
        for (int ww = 0; ww < 8; ++ww) {
            sn += gN[ww * 256 + tid];
            sd += gD[ww * 256 + tid];
        }
        ws[OFF_DNT + g * 256 + tid] = sn;
        ws[OFF_DDT + g * 256 + tid] = sd;
    }
}

// 256 blocks x 256 thr: redundant deterministic N/D reduction, then scale.
__global__ __launch_bounds__(256) void k_fin(const float* __restrict__ ws,
                                             float* __restrict__ out) {
    int m = blockIdx.x, t = threadIdx.x;
    float nv = 0.0f, dv = 0.0f;
#pragma unroll
    for (int j = 0; j < 4; ++j) {
        nv += ws[OFF_NM + j * 256 + t];
        dv += ws[OFF_DM + j * 256 + t];
    }
    for (int o = 32; o; o >>= 1) {
        nv += __shfl_xor(nv, o);
        dv += __shfl_xor(dv, o);
    }
    __shared__ float rn[4], rd[4];
    if ((t & 63) == 0) { rn[t >> 6] = nv; rd[t >> 6] = dv; }
    __syncthreads();
    float N = rn[0] + rn[1] + rn[2] + rn[3];
    float D = rd[0] + rd[1] + rd[2] + rd[3];
    float E = N / D;
    float invD = 1.0f / D;
    float sn = 0.0f, sd = 0.0f;
#pragma unroll
    for (int j = 0; j < 4; ++j) {
        sn += ws[OFF_DNT + (m * 4 + j) * 256 + t];
        sd += ws[OFF_DDT + (m * 4 + j) * 256 + t];
    }
    out[m * 256 + t] = 2.0f * invD * (sn - E * sd);
    if (t == 0) {
        float cn = 0.0f, cd = 0.0f;
#pragma unroll
        for (int j = 0; j < 4; ++j) {
            cn += ws[OFF_CN + m * 4 + j];
            cd += ws[OFF_CD + m * 4 + j];
        }
        out[65536 + m] = 2.0f * invD * (cn - E * cd);
    }
    if (m == 0 && t == 1) out[65792] = E * (1.0f / 256.0f);
}

extern "C" void kernel_launch(void* const* d_in, const int* in_sizes, int n_in,
                              void* d_out, int out_size, void* d_ws, size_t ws_size,
                              hipStream_t stream) {
    const float* theta = (const float*)d_in[0];
    const float* coef = (const float*)d_in[1];
    const float* strengths = (const float*)d_in[4];
    float* out = (float*)d_out;
    float* ws = (float*)d_ws;

    k_prep<<<256, 256, 0, stream>>>(theta, ws);
    k_main<<<1024, 512, 0, stream>>>(coef, strengths, ws);
    k_fin<<<256, 256, 0, stream>>>(ws, out);
}